// Round 1
// baseline (339.588 us; speedup 1.0000x reference)
//
#include <hip/hip_runtime.h>
#include <stdint.h>

// Problem constants (fixed shapes from reference)
#define M_DIM 4096   // 2 * 2048 rows of x
#define K_DIM 4096   // in_features
#define N_DIM 4096   // out_features
#define NUM_SUB (65536 * 8)  // superblocks * 8 subblocks

typedef __bf16 bf16_t;
typedef bf16_t bf16x8 __attribute__((ext_vector_type(8)));
typedef float f32x4 __attribute__((ext_vector_type(4)));

// ---------------------------------------------------------------------------
// Kernel 1: fp32 -> bf16 convert of x (16.7M elements), vectorized 8/thread
// ---------------------------------------------------------------------------
__global__ __launch_bounds__(256) void cvt_x_bf16(const float* __restrict__ x,
                                                  bf16_t* __restrict__ o) {
    size_t i = ((size_t)blockIdx.x * blockDim.x + threadIdx.x) * 8;
    const float4* p = (const float4*)(x + i);
    float4 a = p[0];
    float4 b = p[1];
    bf16x8 v;
    v[0] = (bf16_t)a.x; v[1] = (bf16_t)a.y; v[2] = (bf16_t)a.z; v[3] = (bf16_t)a.w;
    v[4] = (bf16_t)b.x; v[5] = (bf16_t)b.y; v[6] = (bf16_t)b.z; v[7] = (bf16_t)b.w;
    *(bf16x8*)(o + i) = v;
}

// ---------------------------------------------------------------------------
// Kernel 2: Q4_K-style dequant -> bf16 W[N][K].
// Thread t = one subblock (32 weights = 16 packed "bytes" stored as int32).
// w = q * (d*scale/945) + (d*min/63 + dmin)
//   q[2i] = packed[i] & 15 ; q[2i+1] = (packed[i]>>4) & 15
// ---------------------------------------------------------------------------
__global__ __launch_bounds__(256) void dequant_w(const int* __restrict__ packed,
                                                 const float* __restrict__ d,
                                                 const float* __restrict__ dmin,
                                                 const int* __restrict__ scales,
                                                 const int* __restrict__ mins,
                                                 bf16_t* __restrict__ W) {
    int t = blockIdx.x * blockDim.x + threadIdx.x;   // 0 .. NUM_SUB-1
    int s = t >> 3;                                  // superblock
    float ds = d[s];
    float dm = dmin[s];
    float a = ds * (float)scales[t] * (1.0f / 945.0f);   // 945 = 15*63
    float b = ds * (float)mins[t] * (1.0f / 63.0f) + dm;

    const int4* p4 = (const int4*)(packed + (size_t)t * 16);
    bf16_t outv[32];
#pragma unroll
    for (int c = 0; c < 4; ++c) {
        int4 pv = p4[c];
        int vals[4] = {pv.x, pv.y, pv.z, pv.w};
#pragma unroll
        for (int u = 0; u < 4; ++u) {
            int byte = vals[u];
            float lo = (float)(byte & 15) * a + b;
            float hi = (float)((byte >> 4) & 15) * a + b;
            outv[c * 8 + u * 2]     = (bf16_t)lo;
            outv[c * 8 + u * 2 + 1] = (bf16_t)hi;
        }
    }
    bf16_t* dst = W + (size_t)t * 32;
#pragma unroll
    for (int c = 0; c < 4; ++c)
        ((bf16x8*)dst)[c] = ((const bf16x8*)outv)[c];
}

// ---------------------------------------------------------------------------
// Kernel 3: C[M,N] (fp32) = A[M,K](bf16) * B[N,K](bf16)^T  — m97 recipe.
// 128x128 block tile, BK=32, 256 threads = 4 waves (2x2), each wave 64x64 via
// 4x4 grid of 16x16x32 bf16 MFMAs. Staging via global_load_lds width=16
// (wave-uniform LDS base + lane*16, unpadded row-major tiles).
// ---------------------------------------------------------------------------
#define BM 128
#define BN 128
#define BK 32

__device__ __forceinline__ void async_copy16(void* lds, const void* g) {
    __builtin_amdgcn_global_load_lds(
        (const __attribute__((address_space(1))) void*)g,
        (__attribute__((address_space(3))) void*)lds, 16, 0, 0);
}

__global__ __launch_bounds__(256) void gemm_bt(const bf16_t* __restrict__ A,
                                               const bf16_t* __restrict__ B,
                                               float* __restrict__ C) {
    __shared__ bf16_t sA[BM * BK];   // 8 KB, row-major [row][k], NO padding
    __shared__ bf16_t sB[BN * BK];   // 8 KB

    const int tid  = threadIdx.x;
    const int wave = tid >> 6;
    const int lane = tid & 63;
    const int wm = wave >> 1;        // wave row (0/1) -> 64 rows of C
    const int wn = wave & 1;         // wave col (0/1) -> 64 cols of C
    const int r = lane & 15;         // MFMA row/col within 16
    const int q = lane >> 4;         // MFMA k-chunk quad (0..3)

    const int n0 = blockIdx.x * BN;
    const int m0 = blockIdx.y * BM;

    f32x4 acc[4][4] = {};

    // Staging: chunk L = c*256 + tid covers tile row (L>>2), k-chunk (L&3)*8.
    const int rowS = tid >> 2;              // 0..63 (call 0); +64 for call 1
    const int kcS  = (tid & 3) * 8;
    const bf16_t* gA0 = A + (size_t)(m0 + rowS) * K_DIM + kcS;
    const bf16_t* gA1 = gA0 + (size_t)64 * K_DIM;
    const bf16_t* gB0 = B + (size_t)(n0 + rowS) * K_DIM + kcS;
    const bf16_t* gB1 = gB0 + (size_t)64 * K_DIM;
    bf16_t* lA0 = &sA[(wave * 64) * 8];         // wave-uniform LDS bases
    bf16_t* lA1 = &sA[(256 + wave * 64) * 8];
    bf16_t* lB0 = &sB[(wave * 64) * 8];
    bf16_t* lB1 = &sB[(256 + wave * 64) * 8];

    for (int k0 = 0; k0 < K_DIM; k0 += BK) {
        if (k0) __syncthreads();             // protect LDS from overwrite
        async_copy16(lA0, gA0 + k0);
        async_copy16(lA1, gA1 + k0);
        async_copy16(lB0, gB0 + k0);
        async_copy16(lB1, gB1 + k0);
        asm volatile("s_waitcnt vmcnt(0)" ::: "memory");
        __syncthreads();

        bf16x8 af[4], bfr[4];
#pragma unroll
        for (int t = 0; t < 4; ++t) {
            af[t]  = *(const bf16x8*)&sA[(wm * 64 + t * 16 + r) * BK + q * 8];
            bfr[t] = *(const bf16x8*)&sB[(wn * 64 + t * 16 + r) * BK + q * 8];
        }
#pragma unroll
        for (int i = 0; i < 4; ++i)
#pragma unroll
            for (int j = 0; j < 4; ++j)
                acc[i][j] = __builtin_amdgcn_mfma_f32_16x16x32_bf16(
                    af[i], bfr[j], acc[i][j], 0, 0, 0);
    }

    // Epilogue: C/D layout col = lane&15, row = (lane>>4)*4 + reg  [m89]
#pragma unroll
    for (int i = 0; i < 4; ++i) {
        int row = m0 + wm * 64 + i * 16 + q * 4;
#pragma unroll
        for (int j = 0; j < 4; ++j) {
            int col = n0 + wn * 64 + j * 16 + r;
#pragma unroll
            for (int reg = 0; reg < 4; ++reg)
                C[(size_t)(row + reg) * N_DIM + col] = acc[i][j][reg];
        }
    }
}

// ---------------------------------------------------------------------------
// Launch: needs 67 MB of d_ws (33.5 MB x-bf16 + 33.5 MB W-bf16).
// ---------------------------------------------------------------------------
extern "C" void kernel_launch(void* const* d_in, const int* in_sizes, int n_in,
                              void* d_out, int out_size, void* d_ws, size_t ws_size,
                              hipStream_t stream) {
    const float* x      = (const float*)d_in[0];
    const int*   packed = (const int*)d_in[1];
    const float* d      = (const float*)d_in[2];
    const float* dmin   = (const float*)d_in[3];
    const int*   scales = (const int*)d_in[4];
    const int*   mins   = (const int*)d_in[5];
    float* out = (float*)d_out;

    bf16_t* xb = (bf16_t*)d_ws;                       // [M_DIM * K_DIM]
    bf16_t* wb = xb + (size_t)M_DIM * K_DIM;          // [N_DIM * K_DIM]

    cvt_x_bf16<<<(M_DIM * (size_t)K_DIM) / (256 * 8), 256, 0, stream>>>(x, xb);
    dequant_w<<<NUM_SUB / 256, 256, 0, stream>>>(packed, d, dmin, scales, mins, wb);
    gemm_bt<<<dim3(N_DIM / BN, M_DIM / BM), 256, 0, stream>>>(xb, wb, out);
}